// Round 4
// baseline (247.067 us; speedup 1.0000x reference)
//
#include <hip/hip_runtime.h>
#include <stdint.h>

#define FILTER_TH 1.5f
#define SLOTS 20          // per-lane private candidate slots (E=10.4, P(>20)~1.4e-3)
#define STRIDE 21         // odd stride -> max 2-way LDS bank aliasing (free, m136)
#define NB 128            // histogram bins, width 1/32 over [1.5, 5.5)
#define BIN_SCALE 32.0f
#define OVF_CAP 64        // shared per-wave spill list (E[spill]~0.2/row)
#define BCAP 32           // threshold-bin member cap (E~8)
#define DELTA_W 0.2f
#define NITER 5           // float4 loads per pipeline batch (double-buffered)

// Monotone map float -> uint32 (order-preserving) — exact fallback only
static __device__ __forceinline__ unsigned f2u(float x) {
    unsigned b = __float_as_uint(x);
    return (b & 0x80000000u) ? ~b : (b | 0x80000000u);
}
static __device__ __forceinline__ float u2f(unsigned u) {
    unsigned b = (u & 0x80000000u) ? (u & 0x7fffffffu) : ~u;
    return __uint_as_float(b);
}
// In-wave LDS fence: each wave touches only its own LDS slice, so a DS-queue
// drain is all we need — no s_barrier anywhere in this kernel.
static __device__ __forceinline__ void wave_lds_fence() {
    asm volatile("s_waitcnt lgkmcnt(0)" ::: "memory");
}

__global__ __launch_bounds__(256, 6) void dtl_rows(const float* __restrict__ in,
                                                   const int* __restrict__ targets,
                                                   float* __restrict__ ws,
                                                   int M, int N, int K) {
    __shared__ float cand[4][64 * STRIDE];
    __shared__ int   hist[4][NB];
    __shared__ float ovf[4][OVF_CAP];
    __shared__ float bstar[4][BCAP];
    __shared__ int   sc[4][4];   // 0:ovf_cnt 1:bsel 2:chi 3:bcnt

    const int wid = threadIdx.x >> 6;
    const int lane = threadIdx.x & 63;
    const int row = blockIdx.x * 4 + wid;
    if (row >= M) return;        // wave-uniform; no barriers in this kernel

    float* __restrict__ mycand = cand[wid];
    int* __restrict__ myhist = hist[wid];
    float* __restrict__ myovf = ovf[wid];
    float* __restrict__ mybst = bstar[wid];
    int* __restrict__ mys = sc[wid];

    const size_t rowoff = (size_t)row * (size_t)N;
    const float* __restrict__ p = in + rowoff;
    const int tgt = targets[row];

    float posv0 = 0.f;
    if (lane == 0) posv0 = p[tgt];   // issued early; consumed after pass 1

    myhist[lane] = 0;
    myhist[lane + 64] = 0;
    if (lane < 4) mys[lane] = 0;
    wave_lds_fence();

    int myc = 0;
    const int laneBase = lane * STRIDE;

    // Histogram + private-compaction push. NOTE: no target-index check — the
    // target element participates; corrected exactly in value space below.
    auto push = [&](float x) {
        if (x > FILTER_TH) {
            int bin = (int)((x - FILTER_TH) * BIN_SCALE);
            bin = min(bin, NB - 1);
            int slot = min(myc, SLOTS);          // slot==SLOTS is this lane's pad
            mycand[laneBase + slot] = x;         // plain ds_write, no atomic
            if (myc >= SLOTS) {                  // ~never: spill to shared list
                int o = atomicAdd(&mys[0], 1);
                if (o < OVF_CAP) myovf[o] = x;
            }
            myc++;
            atomicAdd(&myhist[bin], 1);          // distributed bins, low conflict
        }
    };

    // ---- Pass 1: filter into private regions + histogram ----
    int a0 = (int)((4 - (rowoff & 3)) & 3);      // odd row stride: align fix
    if (a0 > N) a0 = N;
    const int nv = (N - a0) >> 2;
    const int tail0 = a0 + nv * 4;

    if (lane < a0) push(p[lane]);
    {
        int c = tail0 + lane;
        if (c < N) push(p[c]);
    }

    const float4* __restrict__ pv = (const float4*)(p + a0);
    const int perLane = (nv + 63) >> 6;                  // f4 groups per lane
    const int nBatch = (perLane + NITER - 1) / NITER;

    float4 bufA[NITER], bufB[NITER];
    auto loadBatch = [&](int b, float4* buf) {
#pragma unroll
        for (int it = 0; it < NITER; ++it) {
            int i = (b * NITER + it) * 64 + lane;
            buf[it] = (i < nv) ? pv[i]
                               : make_float4(-1e30f, -1e30f, -1e30f, -1e30f);
        }
    };
    auto procBatch = [&](float4* buf) {
#pragma unroll
        for (int it = 0; it < NITER; ++it) {
            push(buf[it].x); push(buf[it].y); push(buf[it].z); push(buf[it].w);
        }
    };

    if (nBatch > 0) loadBatch(0, bufA);
    for (int b = 0; b < nBatch; ++b) {           // ping-pong pipeline
        float4* cur = (b & 1) ? bufB : bufA;
        float4* nxt = (b & 1) ? bufA : bufB;
        if (b + 1 < nBatch) loadBatch(b + 1, nxt);
        procBatch(cur);
    }
    wave_lds_fence();

    const float posv = __shfl(posv0, 0);
    int nC = myc;                                 // wave total candidate count
#pragma unroll
    for (int off = 32; off > 0; off >>= 1) nC += __shfl_xor(nC, off);
    const int ovfN = mys[0];
    const int Kp = K + (posv > FILTER_TH ? 1 : 0);
    const bool fast = (nC >= Kp) && (ovfN <= OVF_CAP);
    bool done = false;

    if (fast) {
        // ---- threshold bin b* + count-above chi (reverse scan, in-register) --
        int h0 = myhist[lane * 2], h1 = myhist[lane * 2 + 1];
        int cum = h0 + h1;
#pragma unroll
        for (int off = 1; off < 64; off <<= 1) {
            int v = __shfl_down(cum, off);
            if (lane + off < 64) cum += v;
        }
        int cn = __shfl_down(cum, 1);
        if (lane == 63) cn = 0;
        if (cum >= Kp && cn < Kp) {               // unique crossing lane
            int cacc = cn + h1;
            if (cacc >= Kp) { mys[1] = lane * 2 + 1; mys[2] = cn; }
            else            { mys[1] = lane * 2;     mys[2] = cacc; }
        }
        wave_lds_fence();
        const int bsel = mys[1];
        const int chi = mys[2];

        // ---- classify: each lane scans its own region (+ shared spill) ----
        float lsum = 0.f;
        const int mine = min(myc, SLOTS);
        for (int i = 0; i < mine; ++i) {
            float x = mycand[laneBase + i];
            int bin = (int)((x - FILTER_TH) * BIN_SCALE);
            bin = min(bin, NB - 1);
            if (bin > bsel) {
                float e = 1.f + x;
                lsum += e * e;
            } else if (bin == bsel) {
                int b = atomicAdd(&mys[3], 1);
                if (b < BCAP) mybst[b] = x;
            }
        }
        for (int i = lane; i < ovfN; i += 64) {
            float x = myovf[i];
            int bin = (int)((x - FILTER_TH) * BIN_SCALE);
            bin = min(bin, NB - 1);
            if (bin > bsel) {
                float e = 1.f + x;
                lsum += e * e;
            } else if (bin == bsel) {
                int b = atomicAdd(&mys[3], 1);
                if (b < BCAP) mybst[b] = x;
            }
        }
#pragma unroll
        for (int off = 32; off > 0; off >>= 1) lsum += __shfl_down(lsum, off);
        wave_lds_fence();
        const int mB = mys[3];
        if (mB <= BCAP) {
            if (lane == 0) {
                float sum = lsum;
                int need = Kp - chi;              // in [1, mB] by construction
                float T1 = 0.f;
                for (int r = 0; r < need; ++r) {  // top-`need` of tiny bin
                    int bi = 0; float bx = -1e30f;
                    for (int i2 = 0; i2 < mB; ++i2) {
                        float x = mybst[i2];
                        if (x > bx) { bx = x; bi = i2; }
                    }
                    float e = 1.f + bx;
                    sum += e * e;
                    mybst[bi] = -1e30f;
                    T1 = bx;                      // need-th largest = Kp-th overall
                }
                if (posv > FILTER_TH) {
                    // exact exclusion of the target element in value space
                    float ex = (posv >= T1) ? (1.f + posv) : (1.f + T1);
                    sum -= ex * ex;
                }
                float d = 1.f - posv;
                ws[row] = d * d + DELTA_W * sum / (float)K;
            }
            done = true;
        }
    }

    if (!done) {
        // ---- exact global fallback (never hit for N(0,1) data) ----
        // Excludes the target by INDEX; uses K directly.
        unsigned thr = 0;
        for (int bit = 31; bit >= 0; --bit) {
            unsigned trial = thr | (1u << bit);
            int cnt = 0;
            for (int i = lane; i < N; i += 64) {
                if (i == tgt) continue;
                cnt += (f2u(p[i]) >= trial);
            }
            for (int off = 32; off > 0; off >>= 1) cnt += __shfl_down(cnt, off);
            cnt = __shfl(cnt, 0);
            if (cnt >= K) thr = trial;
        }
        int gt = 0; float s = 0.f;
        for (int i = lane; i < N; i += 64) {
            if (i == tgt) continue;
            unsigned u = f2u(p[i]);
            if (u > thr) { gt++; float e = 1.f + u2f(u); s += e * e; }
        }
        for (int off = 32; off > 0; off >>= 1) {
            gt += __shfl_down(gt, off); s += __shfl_down(s, off);
        }
        if (lane == 0) {
            float et = 1.f + u2f(thr);
            float sum = s + (float)(K - gt) * et * et;
            float d = 1.f - posv;
            ws[row] = d * d + DELTA_W * sum / (float)K;
        }
    }
}

__global__ __launch_bounds__(256) void dtl_reduce(const float* __restrict__ ws,
                                                  float* __restrict__ out, int M) {
    __shared__ float sh[4];
    float s = 0.f;
    for (int i = threadIdx.x; i < M; i += 256) s += ws[i];
    for (int off = 32; off > 0; off >>= 1) s += __shfl_down(s, off);
    int wid = threadIdx.x >> 6;
    if ((threadIdx.x & 63) == 0) sh[wid] = s;
    __syncthreads();
    if (threadIdx.x == 0) out[0] = (sh[0] + sh[1] + sh[2] + sh[3]) / (float)M;
}

extern "C" void kernel_launch(void* const* d_in, const int* in_sizes, int n_in,
                              void* d_out, int out_size, void* d_ws, size_t ws_size,
                              hipStream_t stream) {
    const float* in = (const float*)d_in[0];
    const int* tgt = (const int*)d_in[1];
    const int M = in_sizes[1];
    const int N = in_sizes[0] / M;
    int K = (int)(0.01 * (double)(N - 1));  // matches Python int(R*(n-1)) = 100
    if (K < 1) K = 1;

    float* ws = (float*)d_ws;
    float* out = (float*)d_out;

    dtl_rows<<<(M + 3) / 4, 256, 0, stream>>>(in, tgt, ws, M, N, K);
    dtl_reduce<<<1, 256, 0, stream>>>(ws, out, M);
}